// Round 9
// baseline (940.614 us; speedup 1.0000x reference)
//
#include <hip/hip_runtime.h>
#include <stdint.h>

#define V_ELEMS (64*64*64)

typedef _Float16 f16x8 __attribute__((ext_vector_type(8)));
typedef _Float16 f16x4 __attribute__((ext_vector_type(4)));
typedef float f32x4 __attribute__((ext_vector_type(4)));

// LDS layout (bytes):
//   h  : [64][200] f16 @ 0      (25600)  token-major window input
//   qk : [2][64][72] f16 @ 25600 (18432) q cols 0-31, k cols 32-63; aliased by P [2][64][72]
//   vt : [2][32][72] f16 @ 44032 (9216)  aliased by oh [64][72]
// total 53248 -> 3 blocks/CU (160K/3 = 53.3K)
#define SMEM_BYTES 53248
#define H_STRIDE 200
#define QKP_STRIDE 72
#define VT_STRIDE 72
#define OH_STRIDE 72

// workspace layout (bytes):
//   w16 : 294912            (qkv_w + proj_w as f16)
//   hws : 100663296         f16 [4096 win][64 tok][192 c]  (gathered input)
//   ows : 201326592         f32 [4096 win][64 tok][192 c]  (pre-scatter output, f32 keeps abs err identical)
#define W16_BYTES  294912
#define HWS_BYTES  100663296
#define OWS_BYTES  201326592

__global__ void cvt_weights_kernel(const float* __restrict__ qkv_w,
                                   const float* __restrict__ proj_w,
                                   _Float16* __restrict__ w16) {
    int i = blockIdx.x * 256 + threadIdx.x;
    if (i < 110592)      w16[i] = (_Float16)qkv_w[i];
    else if (i < 147456) w16[i] = (_Float16)proj_w[i - 110592];
}

// ---- gather: x (f32 channel-major) -> hws (f16 token-major per window) ----
// block = one (xg, yg) column; reads 192 full z-lines (each byte fetched once,
// fully coalesced), transposes via LDS [zg][c], writes 16 windows x 1536B
// contiguous chunks.
__global__ __launch_bounds__(256, 6)
void gather_kernel(const float* __restrict__ x, _Float16* __restrict__ hws) {
    __shared__ _Float16 L[64 * 200];   // [zg][c], row stride 200 f16 = 400B (16B-aligned)
    const int xg = blockIdx.x >> 6, yg = blockIdx.x & 63;
    const int tid = threadIdx.x;

    // read phase: lane (zq = tid&15) covers one float4 of the z-line of channel c
    {
        const int zq = tid & 15, cb = tid >> 4;
#pragma unroll
        for (int u = 0; u < 12; ++u) {
            const int c = cb + 16 * u;
            const float4 v = *(const float4*)(x + ((size_t)c * 4096 + (size_t)xg * 64 + yg) * 64 + zq * 4);
            const int z0 = zq * 4;
            L[(z0 + 0) * 200 + c] = (_Float16)v.x;
            L[(z0 + 1) * 200 + c] = (_Float16)v.y;
            L[(z0 + 2) * 200 + c] = (_Float16)v.z;
            L[(z0 + 3) * 200 + c] = (_Float16)v.w;
        }
    }
    __syncthreads();

    // write phase: this (xg,yg) is position (i,j) of window column (wx,wy); emit
    // 4 token-rows (zl) x 192c for each of the 16 wz windows, 16B vectors.
    const int tx = (xg + 62) & 63, wx = tx >> 2, i = tx & 3;
    const int ty = (yg + 62) & 63, wy = ty >> 2, j = ty & 3;
    const int wz  = tid & 15;
    const int zl  = (tid >> 4) & 3;
    const int c8b = tid >> 6;
    const int zg  = (wz * 4 + 2 + zl) & 63;
    const size_t base = (size_t)((wx * 16 + wy) * 16 + wz) * 12288 + (size_t)(i * 16 + j * 4 + zl) * 192;
#pragma unroll
    for (int u = 0; u < 6; ++u) {
        const int c8 = c8b + 4 * u;
        f16x8 v = *(const f16x8*)(L + zg * 200 + c8 * 8);
        *(f16x8*)(hws + base + c8 * 8) = v;
    }
}

// ---- scatter: ows (f32 token-major per window) -> out (f32 channel-major) ----
// 1 thread per output float4 (full-line coalesced writes, 201MB exact); 4
// scattered dword reads per thread hit block-local ows lines (each fetched once).
__global__ __launch_bounds__(256, 8)
void scatter_kernel(const float* __restrict__ ows, const float* __restrict__ proj_b,
                    float* __restrict__ out) {
    const uint32_t g = blockIdx.x * 256 + threadIdx.x;
    const int zq = g & 15;
    const int yg = (g >> 4) & 63;
    const int xg = (g >> 10) & 63;
    const int c  = g >> 16;
    const int tx = (xg + 62) & 63, wx = tx >> 2, i = tx & 3;
    const int ty = (yg + 62) & 63, wy = ty >> 2, j = ty & 3;
    const float bias = proj_b[c];
    float4 v;
    float* vp = (float*)&v;
#pragma unroll
    for (int k = 0; k < 4; ++k) {
        const int a  = (zq * 4 + k + 62) & 63;
        const int wz = a >> 2, zl = a & 3;
        const size_t idx = (size_t)((wx * 16 + wy) * 16 + wz) * 12288
                         + (size_t)(i * 16 + j * 4 + zl) * 192 + c;
        vp[k] = ows[idx] + bias;
    }
    *(float4*)(out + ((size_t)c * 4096 + (size_t)xg * 64 + yg) * 64 + zq * 4) = v;
}

// GWS: 1 = read pre-gathered hws (coalesced); 0 = direct scattered gather of x.
// SWS: 1 = write f32 ows (line-aligned, bias deferred to scatter); 0 = direct
//      scattered float2 writes to out (+bias).
template<int GWS, int SWS>
__global__ __launch_bounds__(256, 3)
void win_attn_kernel(const float* __restrict__ x,
                     const _Float16* __restrict__ w16,
                     const float* __restrict__ qkv_b,
                     const float* __restrict__ proj_b,
                     float* __restrict__ out,
                     const _Float16* __restrict__ hws,
                     float* __restrict__ ows)
{
    extern __shared__ char smem[];
    _Float16* h_s  = (_Float16*)smem;                    // [64][200]
    _Float16* qk_s = (_Float16*)(smem + 25600);          // [2][64][72]
    _Float16* P_s  = (_Float16*)(smem + 25600);          // [2][64][72] (alias qk)
    _Float16* vt_s = (_Float16*)(smem + 44032);          // [2][32][72]
    _Float16* oh_s = (_Float16*)(smem + 44032);          // [64][72]   (alias vt)

    const _Float16* qw16 = w16;            // [576][192]
    const _Float16* pw16 = w16 + 110592;   // [192][192]

    const int tid  = threadIdx.x;
    const int wave = tid >> 6;
    const int lane = tid & 63;
    const int l15  = lane & 15;
    const int quad = lane >> 4;

    // per-wave constants for the qkv GEMM column assignment
    const int hh = (wave >> 1) & 1;
    const int dh = wave & 1;

    // XCD-aware swizzle (matters for the GWS=0 direct-gather path; harmless otherwise)
    const int bid = blockIdx.x;
    const int xcd = bid & 7;
    const int s_  = bid >> 3;
    const int wzl = s_ & 3;
    const int gi  = (s_ >> 2) * 8 + xcd;   // 0..1023 = (wx, wy, wz>>2)
    const int wx  = gi >> 6;
    const int wy  = (gi >> 2) & 15;
    const int wz  = ((gi & 3) << 2) | wzl;
    const int W   = (wx * 16 + wy) * 16 + wz;   // natural window id for hws/ows

    // ---- Phase 0: window input -> h_s as f16 ----
    if (GWS) {
        // coalesced 24KB contiguous read of this window from hws
        const size_t wbase = (size_t)W * 12288;
        const int row = tid >> 2, part = tid & 3;
#pragma unroll
        for (int u = 0; u < 6; ++u) {
            const int c8 = part + 4 * u;
            f16x8 v = *(const f16x8*)(hws + wbase + (size_t)row * 192 + c8 * 8);
            *(f16x8*)(h_s + row * H_STRIDE + c8 * 8) = v;
        }
    } else {
        const int p  = tid & 1;          // z-pair index (tokens 2p,2p+1)
        const int r  = (tid >> 1) & 15;  // i = r>>2, j = r&3
        const int cb = tid >> 5;         // 0..7
        const int i = r >> 2, j = r & 3;
        const int xg = (wx*4 + i + 2) & 63;
        const int yg = (wy*4 + j + 2) & 63;
        const int zg = (wz*4 + 2 + 2*p) & 63;   // always even -> no wrap in pair
        const int tok = r*4 + 2*p;
        const size_t sbase = ((size_t)xg*64 + (size_t)yg)*64 + (size_t)zg;
#pragma unroll
        for (int t = 0; t < 24; ++t) {
            int c = cb + 8*t;
            float2 v = *(const float2*)(x + (size_t)c*V_ELEMS + sbase);
            h_s[tok*H_STRIDE + c]     = (_Float16)v.x;
            h_s[(tok+1)*H_STRIDE + c] = (_Float16)v.y;
        }
    }

    f32x4 out_acc[3][4];
#pragma unroll
    for (int a = 0; a < 3; ++a)
#pragma unroll
        for (int b = 0; b < 4; ++b)
            out_acc[a][b] = (f32x4){0.f, 0.f, 0.f, 0.f};

    const f32x4 fzero = {0.f, 0.f, 0.f, 0.f};
    __syncthreads();

#pragma unroll
    for (int hp = 0; hp < 3; ++hp) {   // head pair: heads 2hp, 2hp+1
        // ---- Phase A: qkv GEMM for this head pair ----
        f16x8 bfr[3][6];
        float wbias[3];
#pragma unroll
        for (int wh = 0; wh < 3; ++wh) {
            const int n = wh*192 + (2*hp + hh)*32 + dh*16 + l15;
            wbias[wh] = qkv_b[n];
#pragma unroll
            for (int ks = 0; ks < 6; ++ks)
                bfr[wh][ks] = *(const f16x8*)(qw16 + (size_t)n*192 + ks*32 + quad*8);
        }
        __builtin_amdgcn_s_setprio(1);
#pragma unroll
        for (int rt = 0; rt < 4; ++rt) {
            f16x8 af[6];
#pragma unroll
            for (int ks = 0; ks < 6; ++ks)
                af[ks] = *(const f16x8*)(h_s + (rt*16 + l15)*H_STRIDE + ks*32 + quad*8);
#pragma unroll
            for (int wh = 0; wh < 3; ++wh) {
                f32x4 acc = fzero;
#pragma unroll
                for (int ks = 0; ks < 6; ++ks)
                    acc = __builtin_amdgcn_mfma_f32_16x16x32_f16(af[ks], bfr[wh][ks], acc, 0, 0, 0);
                if (wh == 2) {
                    f16x4 pk;
#pragma unroll
                    for (int r2 = 0; r2 < 4; ++r2) pk[r2] = (_Float16)(acc[r2] + wbias[2]);
                    *(f16x4*)(vt_s + (hh*32 + dh*16 + l15)*VT_STRIDE + rt*16 + quad*4) = pk;
                } else {
                    _Float16* dst = qk_s + hh*64*QKP_STRIDE + (wh == 1 ? 32 : 0);
#pragma unroll
                    for (int r2 = 0; r2 < 4; ++r2)
                        dst[(rt*16 + quad*4 + r2)*QKP_STRIDE + dh*16 + l15] =
                            (_Float16)(acc[r2] + wbias[wh]);
                }
            }
        }
        __builtin_amdgcn_s_setprio(0);
        __syncthreads();   // q/k/vt ready

        // ---- Phase B: S = q k^T, softmax; normalization deferred to Phase C ----
        f32x4 pfr[2][4];
        float inv_r[2][4];
#pragma unroll
        for (int jj = 0; jj < 2; ++jj) {
            f16x8 aq = *(const f16x8*)(qk_s + (jj*64 + wave*16 + l15)*QKP_STRIDE + quad*8);
            f32x4 s[4];
#pragma unroll
            for (int ct = 0; ct < 4; ++ct) {
                f16x8 bk = *(const f16x8*)(qk_s + (jj*64 + ct*16 + l15)*QKP_STRIDE + 32 + quad*8);
                s[ct] = __builtin_amdgcn_mfma_f32_16x16x32_f16(aq, bk, fzero, 0, 0, 0);
            }
            float mx[4];
#pragma unroll
            for (int r = 0; r < 4; ++r) {
                float m = fmaxf(fmaxf(s[0][r], s[1][r]), fmaxf(s[2][r], s[3][r]));
#pragma unroll
                for (int msk = 1; msk < 16; msk <<= 1) m = fmaxf(m, __shfl_xor(m, msk));
                mx[r] = m;
            }
            const float kscale = 0.17677669529663687f * 1.4426950408889634f; // hd^-0.5 * log2(e)
#pragma unroll
            for (int ct = 0; ct < 4; ++ct)
#pragma unroll
                for (int r = 0; r < 4; ++r)
                    s[ct][r] = exp2f((s[ct][r] - mx[r]) * kscale);
#pragma unroll
            for (int r = 0; r < 4; ++r) {
                float sum = s[0][r] + s[1][r] + s[2][r] + s[3][r];
#pragma unroll
                for (int msk = 1; msk < 16; msk <<= 1) sum += __shfl_xor(sum, msk);
                inv_r[jj][r] = 1.0f / sum;
            }
#pragma unroll
            for (int ct = 0; ct < 4; ++ct) pfr[jj][ct] = s[ct];
        }
        __syncthreads();   // all waves done reading q/k -> P may overwrite

#pragma unroll
        for (int jj = 0; jj < 2; ++jj)
#pragma unroll
            for (int ct = 0; ct < 4; ++ct)
#pragma unroll
                for (int r = 0; r < 4; ++r)
                    P_s[(jj*64 + wave*16 + quad*4 + r)*QKP_STRIDE + ct*16 + l15] =
                        (_Float16)pfr[jj][ct][r];

        // ---- Phase C: O = P V  (same-wave LDS RAW -> lgkmcnt, no barrier needed) ----
        f32x4 oacc[2][2];
#pragma unroll
        for (int jj = 0; jj < 2; ++jj)
#pragma unroll
            for (int ct = 0; ct < 2; ++ct) oacc[jj][ct] = fzero;
#pragma unroll
        for (int jj = 0; jj < 2; ++jj)
#pragma unroll
            for (int ks = 0; ks < 2; ++ks) {
                f16x8 ap = *(const f16x8*)(P_s + (jj*64 + wave*16 + l15)*QKP_STRIDE + ks*32 + quad*8);
#pragma unroll
                for (int ct = 0; ct < 2; ++ct) {
                    f16x8 bv = *(const f16x8*)(vt_s + (jj*32 + ct*16 + l15)*VT_STRIDE + ks*32 + quad*8);
                    oacc[jj][ct] = __builtin_amdgcn_mfma_f32_16x16x32_f16(ap, bv, oacc[jj][ct], 0, 0, 0);
                }
            }
        __syncthreads();   // PV done reading vt -> oh may overwrite

        // deferred softmax normalization folded into the f16 convert
#pragma unroll
        for (int jj = 0; jj < 2; ++jj)
#pragma unroll
            for (int ct = 0; ct < 2; ++ct)
#pragma unroll
                for (int r = 0; r < 4; ++r)
                    oh_s[(wave*16 + quad*4 + r)*OH_STRIDE + jj*32 + ct*16 + l15] =
                        (_Float16)(oacc[jj][ct][r] * inv_r[jj][r]);
        __syncthreads();   // oh complete (cross-wave read next)

        // ---- Phase D: proj partial-K accumulate (K slice = this pair's 64 dims) ----
        f16x8 afr[4][2];
#pragma unroll
        for (int rt = 0; rt < 4; ++rt)
#pragma unroll
            for (int ks = 0; ks < 2; ++ks)
                afr[rt][ks] = *(const f16x8*)(oh_s + (rt*16 + l15)*OH_STRIDE + ks*32 + quad*8);
        __builtin_amdgcn_s_setprio(1);
#pragma unroll
        for (int cti = 0; cti < 3; ++cti) {
            const int n = (wave + 4*cti)*16 + l15;
#pragma unroll
            for (int ks = 0; ks < 2; ++ks) {
                f16x8 bf = *(const f16x8*)(pw16 + (size_t)n*192 + hp*64 + ks*32 + quad*8);
#pragma unroll
                for (int rt = 0; rt < 4; ++rt)
                    out_acc[cti][rt] =
                        __builtin_amdgcn_mfma_f32_16x16x32_f16(afr[rt][ks], bf, out_acc[cti][rt], 0, 0, 0);
            }
        }
        __builtin_amdgcn_s_setprio(0);
        __syncthreads();   // next iter overwrites qk (alias P) and vt (alias oh)
    }

    // ---- Epilogue ----
    if (SWS) {
        // f32 token-major window output; per store instruction the wave covers
        // 4 rows x 64B aligned segments -> full HBM lines, no RMW. Bias deferred.
        const size_t obase = (size_t)W * 12288;
#pragma unroll
        for (int cti = 0; cti < 3; ++cti) {
            const int n = (wave + 4*cti)*16 + l15;
#pragma unroll
            for (int rt = 0; rt < 4; ++rt)
#pragma unroll
                for (int r = 0; r < 4; ++r)
                    ows[obase + (size_t)(rt*16 + quad*4 + r)*192 + n] = out_acc[cti][rt][r];
        }
    } else {
        const int zA = wz*4 + 2;          // tokens z=0,1 (max 62 -> no wrap)
        const int zB = (wz*4 + 4) & 63;   // tokens z=2,3 (wraps only as full pair)
        const int yg = (wy*4 + quad + 2) & 63;
#pragma unroll
        for (int cti = 0; cti < 3; ++cti) {
            const int n = (wave + 4*cti)*16 + l15;
            const float bias = proj_b[n];
#pragma unroll
            for (int rt = 0; rt < 4; ++rt) {
                const int xg = (wx*4 + rt + 2) & 63;
                const size_t base = (((size_t)n*64 + (size_t)xg)*64 + (size_t)yg)*64;
                float2 v01 = { out_acc[cti][rt][0] + bias, out_acc[cti][rt][1] + bias };
                float2 v23 = { out_acc[cti][rt][2] + bias, out_acc[cti][rt][3] + bias };
                *(float2*)(out + base + zA) = v01;
                *(float2*)(out + base + zB) = v23;
            }
        }
    }
}

extern "C" void kernel_launch(void* const* d_in, const int* in_sizes, int n_in,
                              void* d_out, int out_size, void* d_ws, size_t ws_size,
                              hipStream_t stream) {
    const float* x      = (const float*)d_in[0];
    const float* qkv_w  = (const float*)d_in[1];
    const float* qkv_b  = (const float*)d_in[2];
    const float* proj_w = (const float*)d_in[3];
    const float* proj_b = (const float*)d_in[4];
    float* out = (float*)d_out;
    char* wsb = (char*)d_ws;
    _Float16* w16 = (_Float16*)wsb;

    cvt_weights_kernel<<<dim3(576), dim3(256), 0, stream>>>(qkv_w, proj_w, w16);

    if (ws_size >= (size_t)W16_BYTES + HWS_BYTES + OWS_BYTES) {
        _Float16* hws = (_Float16*)(wsb + W16_BYTES);
        float*    ows = (float*)(wsb + W16_BYTES + HWS_BYTES);
        gather_kernel<<<dim3(4096), dim3(256), 0, stream>>>(x, hws);
        win_attn_kernel<1,1><<<dim3(4096), dim3(256), SMEM_BYTES, stream>>>(
            x, w16, qkv_b, proj_b, out, hws, ows);
        scatter_kernel<<<dim3(49152), dim3(256), 0, stream>>>(ows, proj_b, out);
    } else if (ws_size >= (size_t)W16_BYTES + OWS_BYTES) {
        float* ows = (float*)(wsb + W16_BYTES);
        win_attn_kernel<0,1><<<dim3(4096), dim3(256), SMEM_BYTES, stream>>>(
            x, w16, qkv_b, proj_b, out, (const _Float16*)nullptr, ows);
        scatter_kernel<<<dim3(49152), dim3(256), 0, stream>>>(ows, proj_b, out);
    } else {
        win_attn_kernel<0,0><<<dim3(4096), dim3(256), SMEM_BYTES, stream>>>(
            x, w16, qkv_b, proj_b, out, (const _Float16*)nullptr, (float*)nullptr);
    }
}

// Round 10
// 624.571 us; speedup vs baseline: 1.5060x; 1.5060x over previous
//
#include <hip/hip_runtime.h>
#include <stdint.h>

#define V_ELEMS (64*64*64)

typedef _Float16 f16x8 __attribute__((ext_vector_type(8)));
typedef _Float16 f16x4 __attribute__((ext_vector_type(4)));
typedef float f32x4 __attribute__((ext_vector_type(4)));

// LDS layout (bytes):
//   h  : [64][200] f16 @ 0      (25600)  token-major window input
//   qk : [2][64][72] f16 @ 25600 (18432) q cols 0-31, k cols 32-63; aliased by P [2][64][72]
//   vt : [2][32][72] f16 @ 44032 (9216)  aliased by oh [64][72]
// total 53248 -> 3 blocks/CU (160K/3 = 53.3K)
#define SMEM_BYTES 53248
#define H_STRIDE 200
#define QKP_STRIDE 72
#define VT_STRIDE 72
#define OH_STRIDE 72

// workspace layout (bytes):
//   w16 : 294912            (qkv_w + proj_w as f16)
//   hws : 100663296         f16 [4096 win][64 tok][192 c]  (gathered input)
//   ows : 201326592         f32 [4096 win][64 tok][192 c]  (pre-scatter output, f32 keeps abs err identical)
#define W16_BYTES  294912
#define HWS_BYTES  100663296
#define OWS_BYTES  201326592

__global__ void cvt_weights_kernel(const float* __restrict__ qkv_w,
                                   const float* __restrict__ proj_w,
                                   _Float16* __restrict__ w16) {
    int i = blockIdx.x * 256 + threadIdx.x;
    if (i < 110592)      w16[i] = (_Float16)qkv_w[i];
    else if (i < 147456) w16[i] = (_Float16)proj_w[i - 110592];
}

// ---- gather: x (f32 channel-major) -> hws (f16 token-major per window) ----
// block = one (xg, yg) column; reads 192 full z-lines (each byte fetched once,
// fully coalesced), transposes via LDS [zg][c], writes 16 windows x 1536B
// contiguous chunks.
__global__ __launch_bounds__(256, 6)
void gather_kernel(const float* __restrict__ x, _Float16* __restrict__ hws) {
    __shared__ _Float16 L[64 * 200];   // [zg][c], row stride 200 f16 = 400B (16B-aligned)
    const int xg = blockIdx.x >> 6, yg = blockIdx.x & 63;
    const int tid = threadIdx.x;

    // read phase: lane (zq = tid&15) covers one float4 of the z-line of channel c
    {
        const int zq = tid & 15, cb = tid >> 4;
#pragma unroll
        for (int u = 0; u < 12; ++u) {
            const int c = cb + 16 * u;
            const float4 v = *(const float4*)(x + ((size_t)c * 4096 + (size_t)xg * 64 + yg) * 64 + zq * 4);
            const int z0 = zq * 4;
            L[(z0 + 0) * 200 + c] = (_Float16)v.x;
            L[(z0 + 1) * 200 + c] = (_Float16)v.y;
            L[(z0 + 2) * 200 + c] = (_Float16)v.z;
            L[(z0 + 3) * 200 + c] = (_Float16)v.w;
        }
    }
    __syncthreads();

    // write phase: this (xg,yg) is position (i,j) of window column (wx,wy); emit
    // 4 token-rows (zl) x 192c for each of the 16 wz windows, 16B vectors.
    const int tx = (xg + 62) & 63, wx = tx >> 2, i = tx & 3;
    const int ty = (yg + 62) & 63, wy = ty >> 2, j = ty & 3;
    const int wz  = tid & 15;
    const int zl  = (tid >> 4) & 3;
    const int c8b = tid >> 6;
    const int zg  = (wz * 4 + 2 + zl) & 63;
    const size_t base = (size_t)((wx * 16 + wy) * 16 + wz) * 12288 + (size_t)(i * 16 + j * 4 + zl) * 192;
#pragma unroll
    for (int u = 0; u < 6; ++u) {
        const int c8 = c8b + 4 * u;
        f16x8 v = *(const f16x8*)(L + zg * 200 + c8 * 8);
        *(f16x8*)(hws + base + c8 * 8) = v;
    }
}

// ---- scatter: ows (f32 token-major per window) -> out (f32 channel-major) ----
// Mirror of gather: block = one (xg,yg) column. Read phase pulls the 16 window
// chunks this column needs — each is 4 CONSECUTIVE token rows x 192 ch = one
// contiguous 3KB run (every ows byte fetched exactly once, coalesced). LDS
// transpose [a][193] (odd stride: bank=(a+c)%32 -> column reads 2-way = free).
// Write phase emits full aligned z-lines (+bias), 201MB exact.
__global__ __launch_bounds__(256, 3)
void scatter_kernel(const float* __restrict__ ows, const float* __restrict__ proj_b,
                    float* __restrict__ out) {
    __shared__ float L[64 * 193];   // [a = wz*4+zl][c], stride 193 f32
    const int xg = blockIdx.x >> 6, yg = blockIdx.x & 63;
    const int tid = threadIdx.x;

    const int tx = (xg + 62) & 63, wx = tx >> 2, i = tx & 3;
    const int ty = (yg + 62) & 63, wy = ty >> 2, j = ty & 3;
    const int Wbase = (wx * 16 + wy) * 16;          // + wz
    const int rowbase = i * 16 + j * 4;             // + zl

    // read phase: 3072 float4s = 16 chunks x 192 float4 (4 rows x 48)
#pragma unroll
    for (int u = 0; u < 12; ++u) {
        const int f  = tid + 256 * u;     // float4 index 0..3071
        const int wz = f / 192;
        const int q  = f % 192;           // zl = q/48, c4 = q%48
        const int zl = q / 48;
        const int c4 = q % 48;
        const float4 v = *(const float4*)(ows
            + (size_t)(Wbase + wz) * 12288 + (size_t)(rowbase + zl) * 192 + c4 * 4);
        const int a = wz * 4 + zl;
        float* Lp = L + a * 193 + c4 * 4;   // odd stride -> not 16B aligned; scalar stores
        Lp[0] = v.x; Lp[1] = v.y; Lp[2] = v.z; Lp[3] = v.w;
    }
    __syncthreads();

    // write phase: thread (c = tid>>4 + 16u, zq = tid&15) -> one float4 of the
    // z-line; lanes 0-15 cover 256B contiguous -> full aligned HBM lines.
    const int zq = tid & 15;
    const int cb = tid >> 4;
#pragma unroll
    for (int u = 0; u < 12; ++u) {
        const int c = cb + 16 * u;
        const float bias = proj_b[c];
        float4 v;
        float* vp = (float*)&v;
#pragma unroll
        for (int k = 0; k < 4; ++k) {
            const int a = (zq * 4 + k + 62) & 63;   // inverse cyclic shift in z
            vp[k] = L[a * 193 + c] + bias;
        }
        *(float4*)(out + ((size_t)c * 4096 + (size_t)xg * 64 + yg) * 64 + zq * 4) = v;
    }
}

// GWS: 1 = read pre-gathered hws (coalesced); 0 = direct scattered gather of x.
// SWS: 1 = write f32 ows (line-aligned, bias deferred to scatter); 0 = direct
//      scattered float2 writes to out (+bias).
template<int GWS, int SWS>
__global__ __launch_bounds__(256, 3)
void win_attn_kernel(const float* __restrict__ x,
                     const _Float16* __restrict__ w16,
                     const float* __restrict__ qkv_b,
                     const float* __restrict__ proj_b,
                     float* __restrict__ out,
                     const _Float16* __restrict__ hws,
                     float* __restrict__ ows)
{
    extern __shared__ char smem[];
    _Float16* h_s  = (_Float16*)smem;                    // [64][200]
    _Float16* qk_s = (_Float16*)(smem + 25600);          // [2][64][72]
    _Float16* P_s  = (_Float16*)(smem + 25600);          // [2][64][72] (alias qk)
    _Float16* vt_s = (_Float16*)(smem + 44032);          // [2][32][72]
    _Float16* oh_s = (_Float16*)(smem + 44032);          // [64][72]   (alias vt)

    const _Float16* qw16 = w16;            // [576][192]
    const _Float16* pw16 = w16 + 110592;   // [192][192]

    const int tid  = threadIdx.x;
    const int wave = tid >> 6;
    const int lane = tid & 63;
    const int l15  = lane & 15;
    const int quad = lane >> 4;

    // per-wave constants for the qkv GEMM column assignment
    const int hh = (wave >> 1) & 1;
    const int dh = wave & 1;

    // XCD-aware swizzle (matters for the GWS=0 direct-gather path; harmless otherwise)
    const int bid = blockIdx.x;
    const int xcd = bid & 7;
    const int s_  = bid >> 3;
    const int wzl = s_ & 3;
    const int gi  = (s_ >> 2) * 8 + xcd;   // 0..1023 = (wx, wy, wz>>2)
    const int wx  = gi >> 6;
    const int wy  = (gi >> 2) & 15;
    const int wz  = ((gi & 3) << 2) | wzl;
    const int W   = (wx * 16 + wy) * 16 + wz;   // natural window id for hws/ows

    // ---- Phase 0: window input -> h_s as f16 ----
    if (GWS) {
        // coalesced 24KB contiguous read of this window from hws
        const size_t wbase = (size_t)W * 12288;
        const int row = tid >> 2, part = tid & 3;
#pragma unroll
        for (int u = 0; u < 6; ++u) {
            const int c8 = part + 4 * u;
            f16x8 v = *(const f16x8*)(hws + wbase + (size_t)row * 192 + c8 * 8);
            *(f16x8*)(h_s + row * H_STRIDE + c8 * 8) = v;
        }
    } else {
        const int p  = tid & 1;          // z-pair index (tokens 2p,2p+1)
        const int r  = (tid >> 1) & 15;  // i = r>>2, j = r&3
        const int cb = tid >> 5;         // 0..7
        const int i = r >> 2, j = r & 3;
        const int xg = (wx*4 + i + 2) & 63;
        const int yg = (wy*4 + j + 2) & 63;
        const int zg = (wz*4 + 2 + 2*p) & 63;   // always even -> no wrap in pair
        const int tok = r*4 + 2*p;
        const size_t sbase = ((size_t)xg*64 + (size_t)yg)*64 + (size_t)zg;
#pragma unroll
        for (int t = 0; t < 24; ++t) {
            int c = cb + 8*t;
            float2 v = *(const float2*)(x + (size_t)c*V_ELEMS + sbase);
            h_s[tok*H_STRIDE + c]     = (_Float16)v.x;
            h_s[(tok+1)*H_STRIDE + c] = (_Float16)v.y;
        }
    }

    f32x4 out_acc[3][4];
#pragma unroll
    for (int a = 0; a < 3; ++a)
#pragma unroll
        for (int b = 0; b < 4; ++b)
            out_acc[a][b] = (f32x4){0.f, 0.f, 0.f, 0.f};

    const f32x4 fzero = {0.f, 0.f, 0.f, 0.f};
    __syncthreads();

#pragma unroll
    for (int hp = 0; hp < 3; ++hp) {   // head pair: heads 2hp, 2hp+1
        // ---- Phase A: qkv GEMM for this head pair ----
        f16x8 bfr[3][6];
        float wbias[3];
#pragma unroll
        for (int wh = 0; wh < 3; ++wh) {
            const int n = wh*192 + (2*hp + hh)*32 + dh*16 + l15;
            wbias[wh] = qkv_b[n];
#pragma unroll
            for (int ks = 0; ks < 6; ++ks)
                bfr[wh][ks] = *(const f16x8*)(qw16 + (size_t)n*192 + ks*32 + quad*8);
        }
        __builtin_amdgcn_s_setprio(1);
#pragma unroll
        for (int rt = 0; rt < 4; ++rt) {
            f16x8 af[6];
#pragma unroll
            for (int ks = 0; ks < 6; ++ks)
                af[ks] = *(const f16x8*)(h_s + (rt*16 + l15)*H_STRIDE + ks*32 + quad*8);
#pragma unroll
            for (int wh = 0; wh < 3; ++wh) {
                f32x4 acc = fzero;
#pragma unroll
                for (int ks = 0; ks < 6; ++ks)
                    acc = __builtin_amdgcn_mfma_f32_16x16x32_f16(af[ks], bfr[wh][ks], acc, 0, 0, 0);
                if (wh == 2) {
                    f16x4 pk;
#pragma unroll
                    for (int r2 = 0; r2 < 4; ++r2) pk[r2] = (_Float16)(acc[r2] + wbias[2]);
                    *(f16x4*)(vt_s + (hh*32 + dh*16 + l15)*VT_STRIDE + rt*16 + quad*4) = pk;
                } else {
                    _Float16* dst = qk_s + hh*64*QKP_STRIDE + (wh == 1 ? 32 : 0);
#pragma unroll
                    for (int r2 = 0; r2 < 4; ++r2)
                        dst[(rt*16 + quad*4 + r2)*QKP_STRIDE + dh*16 + l15] =
                            (_Float16)(acc[r2] + wbias[wh]);
                }
            }
        }
        __builtin_amdgcn_s_setprio(0);
        __syncthreads();   // q/k/vt ready

        // ---- Phase B: S = q k^T, softmax; normalization deferred to Phase C ----
        f32x4 pfr[2][4];
        float inv_r[2][4];
#pragma unroll
        for (int jj = 0; jj < 2; ++jj) {
            f16x8 aq = *(const f16x8*)(qk_s + (jj*64 + wave*16 + l15)*QKP_STRIDE + quad*8);
            f32x4 s[4];
#pragma unroll
            for (int ct = 0; ct < 4; ++ct) {
                f16x8 bk = *(const f16x8*)(qk_s + (jj*64 + ct*16 + l15)*QKP_STRIDE + 32 + quad*8);
                s[ct] = __builtin_amdgcn_mfma_f32_16x16x32_f16(aq, bk, fzero, 0, 0, 0);
            }
            float mx[4];
#pragma unroll
            for (int r = 0; r < 4; ++r) {
                float m = fmaxf(fmaxf(s[0][r], s[1][r]), fmaxf(s[2][r], s[3][r]));
#pragma unroll
                for (int msk = 1; msk < 16; msk <<= 1) m = fmaxf(m, __shfl_xor(m, msk));
                mx[r] = m;
            }
            const float kscale = 0.17677669529663687f * 1.4426950408889634f; // hd^-0.5 * log2(e)
#pragma unroll
            for (int ct = 0; ct < 4; ++ct)
#pragma unroll
                for (int r = 0; r < 4; ++r)
                    s[ct][r] = exp2f((s[ct][r] - mx[r]) * kscale);
#pragma unroll
            for (int r = 0; r < 4; ++r) {
                float sum = s[0][r] + s[1][r] + s[2][r] + s[3][r];
#pragma unroll
                for (int msk = 1; msk < 16; msk <<= 1) sum += __shfl_xor(sum, msk);
                inv_r[jj][r] = 1.0f / sum;
            }
#pragma unroll
            for (int ct = 0; ct < 4; ++ct) pfr[jj][ct] = s[ct];
        }
        __syncthreads();   // all waves done reading q/k -> P may overwrite

#pragma unroll
        for (int jj = 0; jj < 2; ++jj)
#pragma unroll
            for (int ct = 0; ct < 4; ++ct)
#pragma unroll
                for (int r = 0; r < 4; ++r)
                    P_s[(jj*64 + wave*16 + quad*4 + r)*QKP_STRIDE + ct*16 + l15] =
                        (_Float16)pfr[jj][ct][r];

        // ---- Phase C: O = P V  (same-wave LDS RAW -> lgkmcnt, no barrier needed) ----
        f32x4 oacc[2][2];
#pragma unroll
        for (int jj = 0; jj < 2; ++jj)
#pragma unroll
            for (int ct = 0; ct < 2; ++ct) oacc[jj][ct] = fzero;
#pragma unroll
        for (int jj = 0; jj < 2; ++jj)
#pragma unroll
            for (int ks = 0; ks < 2; ++ks) {
                f16x8 ap = *(const f16x8*)(P_s + (jj*64 + wave*16 + l15)*QKP_STRIDE + ks*32 + quad*8);
#pragma unroll
                for (int ct = 0; ct < 2; ++ct) {
                    f16x8 bv = *(const f16x8*)(vt_s + (jj*32 + ct*16 + l15)*VT_STRIDE + ks*32 + quad*8);
                    oacc[jj][ct] = __builtin_amdgcn_mfma_f32_16x16x32_f16(ap, bv, oacc[jj][ct], 0, 0, 0);
                }
            }
        __syncthreads();   // PV done reading vt -> oh may overwrite

        // deferred softmax normalization folded into the f16 convert
#pragma unroll
        for (int jj = 0; jj < 2; ++jj)
#pragma unroll
            for (int ct = 0; ct < 2; ++ct)
#pragma unroll
                for (int r = 0; r < 4; ++r)
                    oh_s[(wave*16 + quad*4 + r)*OH_STRIDE + jj*32 + ct*16 + l15] =
                        (_Float16)(oacc[jj][ct][r] * inv_r[jj][r]);
        __syncthreads();   // oh complete (cross-wave read next)

        // ---- Phase D: proj partial-K accumulate (K slice = this pair's 64 dims) ----
        f16x8 afr[4][2];
#pragma unroll
        for (int rt = 0; rt < 4; ++rt)
#pragma unroll
            for (int ks = 0; ks < 2; ++ks)
                afr[rt][ks] = *(const f16x8*)(oh_s + (rt*16 + l15)*OH_STRIDE + ks*32 + quad*8);
        __builtin_amdgcn_s_setprio(1);
#pragma unroll
        for (int cti = 0; cti < 3; ++cti) {
            const int n = (wave + 4*cti)*16 + l15;
#pragma unroll
            for (int ks = 0; ks < 2; ++ks) {
                f16x8 bf = *(const f16x8*)(pw16 + (size_t)n*192 + hp*64 + ks*32 + quad*8);
#pragma unroll
                for (int rt = 0; rt < 4; ++rt)
                    out_acc[cti][rt] =
                        __builtin_amdgcn_mfma_f32_16x16x32_f16(afr[rt][ks], bf, out_acc[cti][rt], 0, 0, 0);
            }
        }
        __builtin_amdgcn_s_setprio(0);
        __syncthreads();   // next iter overwrites qk (alias P) and vt (alias oh)
    }

    // ---- Epilogue ----
    if (SWS) {
        // f32 token-major window output; per store instruction the wave covers
        // 4 rows x 64B aligned segments -> full HBM lines, no RMW. Bias deferred.
        const size_t obase = (size_t)W * 12288;
#pragma unroll
        for (int cti = 0; cti < 3; ++cti) {
            const int n = (wave + 4*cti)*16 + l15;
#pragma unroll
            for (int rt = 0; rt < 4; ++rt)
#pragma unroll
                for (int r = 0; r < 4; ++r)
                    ows[obase + (size_t)(rt*16 + quad*4 + r)*192 + n] = out_acc[cti][rt][r];
        }
    } else {
        const int zA = wz*4 + 2;          // tokens z=0,1 (max 62 -> no wrap)
        const int zB = (wz*4 + 4) & 63;   // tokens z=2,3 (wraps only as full pair)
        const int yg = (wy*4 + quad + 2) & 63;
#pragma unroll
        for (int cti = 0; cti < 3; ++cti) {
            const int n = (wave + 4*cti)*16 + l15;
            const float bias = proj_b[n];
#pragma unroll
            for (int rt = 0; rt < 4; ++rt) {
                const int xg = (wx*4 + rt + 2) & 63;
                const size_t base = (((size_t)n*64 + (size_t)xg)*64 + (size_t)yg)*64;
                float2 v01 = { out_acc[cti][rt][0] + bias, out_acc[cti][rt][1] + bias };
                float2 v23 = { out_acc[cti][rt][2] + bias, out_acc[cti][rt][3] + bias };
                *(float2*)(out + base + zA) = v01;
                *(float2*)(out + base + zB) = v23;
            }
        }
    }
}

extern "C" void kernel_launch(void* const* d_in, const int* in_sizes, int n_in,
                              void* d_out, int out_size, void* d_ws, size_t ws_size,
                              hipStream_t stream) {
    const float* x      = (const float*)d_in[0];
    const float* qkv_w  = (const float*)d_in[1];
    const float* qkv_b  = (const float*)d_in[2];
    const float* proj_w = (const float*)d_in[3];
    const float* proj_b = (const float*)d_in[4];
    float* out = (float*)d_out;
    char* wsb = (char*)d_ws;
    _Float16* w16 = (_Float16*)wsb;

    cvt_weights_kernel<<<dim3(576), dim3(256), 0, stream>>>(qkv_w, proj_w, w16);

    if (ws_size >= (size_t)W16_BYTES + HWS_BYTES + OWS_BYTES) {
        _Float16* hws = (_Float16*)(wsb + W16_BYTES);
        float*    ows = (float*)(wsb + W16_BYTES + HWS_BYTES);
        gather_kernel<<<dim3(4096), dim3(256), 0, stream>>>(x, hws);
        win_attn_kernel<1,1><<<dim3(4096), dim3(256), SMEM_BYTES, stream>>>(
            x, w16, qkv_b, proj_b, out, hws, ows);
        scatter_kernel<<<dim3(4096), dim3(256), 0, stream>>>(ows, proj_b, out);
    } else if (ws_size >= (size_t)W16_BYTES + OWS_BYTES) {
        float* ows = (float*)(wsb + W16_BYTES);
        win_attn_kernel<0,1><<<dim3(4096), dim3(256), SMEM_BYTES, stream>>>(
            x, w16, qkv_b, proj_b, out, (const _Float16*)nullptr, ows);
        scatter_kernel<<<dim3(4096), dim3(256), 0, stream>>>(ows, proj_b, out);
    } else {
        win_attn_kernel<0,0><<<dim3(4096), dim3(256), SMEM_BYTES, stream>>>(
            x, w16, qkv_b, proj_b, out, (const _Float16*)nullptr, (float*)nullptr);
    }
}

// Round 12
// 621.087 us; speedup vs baseline: 1.5145x; 1.0056x over previous
//
#include <hip/hip_runtime.h>
#include <stdint.h>

#define V_ELEMS (64*64*64)

typedef _Float16 f16x8 __attribute__((ext_vector_type(8)));
typedef _Float16 f16x4 __attribute__((ext_vector_type(4)));
typedef float f32x4 __attribute__((ext_vector_type(4)));

// LDS layout (bytes):
//   h  : [64][200] f16 @ 0      (25600)  token-major window input
//   qk : [2][64][72] f16 @ 25600 (18432) q cols 0-31, k cols 32-63; aliased by P [2][64][72]
//   vt : [2][32][72] f16 @ 44032 (9216)  aliased by oh [64][72]
// total 53248 -> 3 blocks/CU (160K/3 = 53.3K)
#define SMEM_BYTES 53248
#define H_STRIDE 200
#define QKP_STRIDE 72
#define VT_STRIDE 72
#define OH_STRIDE 72

// workspace layout (bytes):
//   w16 : 294912            (qkv_w + proj_w as f16)
//   hws : 100663296         f16 [4096 win][64 tok][192 c]  (gathered input)
//   ows : 201326592         f32 [4096 win][64 tok][192 c]  (pre-scatter output, f32 keeps abs err identical)
#define W16_BYTES  294912
#define HWS_BYTES  100663296
#define OWS_BYTES  201326592

__global__ void cvt_weights_kernel(const float* __restrict__ qkv_w,
                                   const float* __restrict__ proj_w,
                                   _Float16* __restrict__ w16) {
    int i = blockIdx.x * 256 + threadIdx.x;
    if (i < 110592)      w16[i] = (_Float16)qkv_w[i];
    else if (i < 147456) w16[i] = (_Float16)proj_w[i - 110592];
}

// ---- gather: x (f32 channel-major) -> hws (f16 token-major per window) ----
// block = one (xg, yg) column; reads 192 full z-lines (each byte fetched once,
// fully coalesced), transposes via LDS [zg][c].
// Write phase (fixed in R11): chunk index in LOW bits so each wave writes
// 1024B contiguous within one window's 3KB run — full-line writes, no RMW.
__global__ __launch_bounds__(256, 6)
void gather_kernel(const float* __restrict__ x, _Float16* __restrict__ hws) {
    __shared__ _Float16 L[64 * 200];   // [zg][c], row stride 200 f16 = 400B (16B-aligned)
    const int xg = blockIdx.x >> 6, yg = blockIdx.x & 63;
    const int tid = threadIdx.x;

    // read phase: lane (zq = tid&15) covers one float4 of the z-line of channel c
    {
        const int zq = tid & 15, cb = tid >> 4;
#pragma unroll
        for (int u = 0; u < 12; ++u) {
            const int c = cb + 16 * u;
            const float4 v = *(const float4*)(x + ((size_t)c * 4096 + (size_t)xg * 64 + yg) * 64 + zq * 4);
            const int z0 = zq * 4;
            L[(z0 + 0) * 200 + c] = (_Float16)v.x;
            L[(z0 + 1) * 200 + c] = (_Float16)v.y;
            L[(z0 + 2) * 200 + c] = (_Float16)v.z;
            L[(z0 + 3) * 200 + c] = (_Float16)v.w;
        }
    }
    __syncthreads();

    // write phase: 1536 16B-chunks = 16 windows x 4 rows x 24 chunks.
    // t = u*256+tid with ch in low bits -> consecutive lanes write consecutive
    // 16B chunks (wave = 1024B contiguous run inside a window chunk).
    const int tx = (xg + 62) & 63, wx = tx >> 2, i = tx & 3;
    const int ty = (yg + 62) & 63, wy = ty >> 2, j = ty & 3;
    const int rowbase = i * 16 + j * 4;
#pragma unroll
    for (int u = 0; u < 6; ++u) {
        const int t   = u * 256 + tid;    // 0..1535
        const int wz  = t / 96;           // 16 windows
        const int rem = t % 96;
        const int zl  = rem / 24;         // 4 token-rows per window
        const int ch  = rem % 24;         // 24 x 16B chunks per row (192 f16)
        const int zg  = (wz * 4 + 2 + zl) & 63;
        const size_t dst = (size_t)((wx * 16 + wy) * 16 + wz) * 12288
                         + (size_t)(rowbase + zl) * 192 + ch * 8;
        *(f16x8*)(hws + dst) = *(const f16x8*)(L + zg * 200 + ch * 8);
    }
}

// ---- scatter: ows (f32 token-major per window) -> out (f32 channel-major) ----
// Mirror of gather: block = one (xg,yg) column. Two 96-channel passes so LDS
// is [64][97] f32 = 24.8KB -> 6 blocks/CU (R11: was 49.4KB / 3 blocks).
// Read phase: 16 window-chunks, each 4 consecutive rows x 96ch = 384B-contig
// runs, every ows byte fetched exactly once. Write: full aligned z-lines
// (+bias), 201MB exact.
__global__ __launch_bounds__(256, 6)
void scatter_kernel(const float* __restrict__ ows, const float* __restrict__ proj_b,
                    float* __restrict__ out) {
    __shared__ float L[64 * 97];   // [a = wz*4+zl][c_local], stride 97 f32
    const int xg = blockIdx.x >> 6, yg = blockIdx.x & 63;
    const int tid = threadIdx.x;

    const int tx = (xg + 62) & 63, wx = tx >> 2, i = tx & 3;
    const int ty = (yg + 62) & 63, wy = ty >> 2, j = ty & 3;
    const int Wbase = (wx * 16 + wy) * 16;          // + wz
    const int rowbase = i * 16 + j * 4;             // + zl

    const int zq = tid & 15;    // write-phase z-quad
    const int cb = tid >> 4;    // write-phase channel base (0..15)

#pragma unroll
    for (int p = 0; p < 2; ++p) {
        if (p) __syncthreads();   // pass-0 write phase done reading L

        // read phase: 1536 float4 = 16 chunks x (4 rows x 24 float4 of 96 ch)
#pragma unroll
        for (int u = 0; u < 6; ++u) {
            const int t   = u * 256 + tid;   // 0..1535
            const int wz  = t / 96;
            const int rem = t % 96;
            const int zl  = rem / 24;
            const int c4  = rem % 24;        // float4 idx within 96 channels
            const float4 v = *(const float4*)(ows
                + (size_t)(Wbase + wz) * 12288 + (size_t)(rowbase + zl) * 192
                + p * 96 + c4 * 4);
            float* Lp = L + (wz * 4 + zl) * 97 + c4 * 4;
            Lp[0] = v.x; Lp[1] = v.y; Lp[2] = v.z; Lp[3] = v.w;
        }
        __syncthreads();

        // write phase: thread (c_local = cb+16u, zq) -> one float4 of z-line;
        // lanes 0-15 cover 256B contiguous -> full aligned HBM lines.
#pragma unroll
        for (int u = 0; u < 6; ++u) {
            const int cl = cb + 16 * u;     // 0..95
            const int c  = p * 96 + cl;
            const float bias = proj_b[c];
            float4 v;
            float* vp = (float*)&v;
#pragma unroll
            for (int k = 0; k < 4; ++k) {
                const int a = (zq * 4 + k + 62) & 63;   // inverse cyclic shift in z
                vp[k] = L[a * 97 + cl] + bias;
            }
            *(float4*)(out + ((size_t)c * 4096 + (size_t)xg * 64 + yg) * 64 + zq * 4) = v;
        }
    }
}

// GWS: 1 = read pre-gathered hws (coalesced); 0 = direct scattered gather of x.
// SWS: 1 = write f32 ows (line-aligned, bias deferred to scatter); 0 = direct
//      scattered float2 writes to out (+bias).
template<int GWS, int SWS>
__global__ __launch_bounds__(256, 3)
void win_attn_kernel(const float* __restrict__ x,
                     const _Float16* __restrict__ w16,
                     const float* __restrict__ qkv_b,
                     const float* __restrict__ proj_b,
                     float* __restrict__ out,
                     const _Float16* __restrict__ hws,
                     float* __restrict__ ows)
{
    extern __shared__ char smem[];
    _Float16* h_s  = (_Float16*)smem;                    // [64][200]
    _Float16* qk_s = (_Float16*)(smem + 25600);          // [2][64][72]
    _Float16* P_s  = (_Float16*)(smem + 25600);          // [2][64][72] (alias qk)
    _Float16* vt_s = (_Float16*)(smem + 44032);          // [2][32][72]
    _Float16* oh_s = (_Float16*)(smem + 44032);          // [64][72]   (alias vt)

    const _Float16* qw16 = w16;            // [576][192]
    const _Float16* pw16 = w16 + 110592;   // [192][192]

    const int tid  = threadIdx.x;
    const int wave = tid >> 6;
    const int lane = tid & 63;
    const int l15  = lane & 15;
    const int quad = lane >> 4;

    // per-wave constants for the qkv GEMM column assignment
    const int hh = (wave >> 1) & 1;
    const int dh = wave & 1;

    // XCD-aware swizzle (matters for the GWS=0 direct-gather path; harmless otherwise)
    const int bid = blockIdx.x;
    const int xcd = bid & 7;
    const int s_  = bid >> 3;
    const int wzl = s_ & 3;
    const int gi  = (s_ >> 2) * 8 + xcd;   // 0..1023 = (wx, wy, wz>>2)
    const int wx  = gi >> 6;
    const int wy  = (gi >> 2) & 15;
    const int wz  = ((gi & 3) << 2) | wzl;
    const int W   = (wx * 16 + wy) * 16 + wz;   // natural window id for hws/ows

    // ---- Phase 0: window input -> h_s as f16 ----
    if (GWS) {
        // coalesced 24KB contiguous read of this window from hws
        const size_t wbase = (size_t)W * 12288;
        const int row = tid >> 2, part = tid & 3;
#pragma unroll
        for (int u = 0; u < 6; ++u) {
            const int c8 = part + 4 * u;
            f16x8 v = *(const f16x8*)(hws + wbase + (size_t)row * 192 + c8 * 8);
            *(f16x8*)(h_s + row * H_STRIDE + c8 * 8) = v;
        }
    } else {
        const int p  = tid & 1;          // z-pair index (tokens 2p,2p+1)
        const int r  = (tid >> 1) & 15;  // i = r>>2, j = r&3
        const int cb = tid >> 5;         // 0..7
        const int i = r >> 2, j = r & 3;
        const int xg = (wx*4 + i + 2) & 63;
        const int yg = (wy*4 + j + 2) & 63;
        const int zg = (wz*4 + 2 + 2*p) & 63;   // always even -> no wrap in pair
        const int tok = r*4 + 2*p;
        const size_t sbase = ((size_t)xg*64 + (size_t)yg)*64 + (size_t)zg;
#pragma unroll
        for (int t = 0; t < 24; ++t) {
            int c = cb + 8*t;
            float2 v = *(const float2*)(x + (size_t)c*V_ELEMS + sbase);
            h_s[tok*H_STRIDE + c]     = (_Float16)v.x;
            h_s[(tok+1)*H_STRIDE + c] = (_Float16)v.y;
        }
    }

    f32x4 out_acc[3][4];
#pragma unroll
    for (int a = 0; a < 3; ++a)
#pragma unroll
        for (int b = 0; b < 4; ++b)
            out_acc[a][b] = (f32x4){0.f, 0.f, 0.f, 0.f};

    const f32x4 fzero = {0.f, 0.f, 0.f, 0.f};
    __syncthreads();

#pragma unroll
    for (int hp = 0; hp < 3; ++hp) {   // head pair: heads 2hp, 2hp+1
        // ---- Phase A: qkv GEMM for this head pair ----
        f16x8 bfr[3][6];
        float wbias[3];
#pragma unroll
        for (int wh = 0; wh < 3; ++wh) {
            const int n = wh*192 + (2*hp + hh)*32 + dh*16 + l15;
            wbias[wh] = qkv_b[n];
#pragma unroll
            for (int ks = 0; ks < 6; ++ks)
                bfr[wh][ks] = *(const f16x8*)(qw16 + (size_t)n*192 + ks*32 + quad*8);
        }
        __builtin_amdgcn_s_setprio(1);
#pragma unroll
        for (int rt = 0; rt < 4; ++rt) {
            f16x8 af[6];
#pragma unroll
            for (int ks = 0; ks < 6; ++ks)
                af[ks] = *(const f16x8*)(h_s + (rt*16 + l15)*H_STRIDE + ks*32 + quad*8);
#pragma unroll
            for (int wh = 0; wh < 3; ++wh) {
                f32x4 acc = fzero;
#pragma unroll
                for (int ks = 0; ks < 6; ++ks)
                    acc = __builtin_amdgcn_mfma_f32_16x16x32_f16(af[ks], bfr[wh][ks], acc, 0, 0, 0);
                if (wh == 2) {
                    f16x4 pk;
#pragma unroll
                    for (int r2 = 0; r2 < 4; ++r2) pk[r2] = (_Float16)(acc[r2] + wbias[2]);
                    *(f16x4*)(vt_s + (hh*32 + dh*16 + l15)*VT_STRIDE + rt*16 + quad*4) = pk;
                } else {
                    _Float16* dst = qk_s + hh*64*QKP_STRIDE + (wh == 1 ? 32 : 0);
#pragma unroll
                    for (int r2 = 0; r2 < 4; ++r2)
                        dst[(rt*16 + quad*4 + r2)*QKP_STRIDE + dh*16 + l15] =
                            (_Float16)(acc[r2] + wbias[wh]);
                }
            }
        }
        __builtin_amdgcn_s_setprio(0);
        __syncthreads();   // q/k/vt ready

        // ---- Phase B: S = q k^T, softmax; normalization deferred to Phase C ----
        f32x4 pfr[2][4];
        float inv_r[2][4];
#pragma unroll
        for (int jj = 0; jj < 2; ++jj) {
            f16x8 aq = *(const f16x8*)(qk_s + (jj*64 + wave*16 + l15)*QKP_STRIDE + quad*8);
            f32x4 s[4];
#pragma unroll
            for (int ct = 0; ct < 4; ++ct) {
                f16x8 bk = *(const f16x8*)(qk_s + (jj*64 + ct*16 + l15)*QKP_STRIDE + 32 + quad*8);
                s[ct] = __builtin_amdgcn_mfma_f32_16x16x32_f16(aq, bk, fzero, 0, 0, 0);
            }
            float mx[4];
#pragma unroll
            for (int r = 0; r < 4; ++r) {
                float m = fmaxf(fmaxf(s[0][r], s[1][r]), fmaxf(s[2][r], s[3][r]));
#pragma unroll
                for (int msk = 1; msk < 16; msk <<= 1) m = fmaxf(m, __shfl_xor(m, msk));
                mx[r] = m;
            }
            const float kscale = 0.17677669529663687f * 1.4426950408889634f; // hd^-0.5 * log2(e)
#pragma unroll
            for (int ct = 0; ct < 4; ++ct)
#pragma unroll
                for (int r = 0; r < 4; ++r)
                    s[ct][r] = exp2f((s[ct][r] - mx[r]) * kscale);
#pragma unroll
            for (int r = 0; r < 4; ++r) {
                float sum = s[0][r] + s[1][r] + s[2][r] + s[3][r];
#pragma unroll
                for (int msk = 1; msk < 16; msk <<= 1) sum += __shfl_xor(sum, msk);
                inv_r[jj][r] = 1.0f / sum;
            }
#pragma unroll
            for (int ct = 0; ct < 4; ++ct) pfr[jj][ct] = s[ct];
        }
        __syncthreads();   // all waves done reading q/k -> P may overwrite

#pragma unroll
        for (int jj = 0; jj < 2; ++jj)
#pragma unroll
            for (int ct = 0; ct < 4; ++ct)
#pragma unroll
                for (int r = 0; r < 4; ++r)
                    P_s[(jj*64 + wave*16 + quad*4 + r)*QKP_STRIDE + ct*16 + l15] =
                        (_Float16)pfr[jj][ct][r];

        // ---- Phase C: O = P V  (same-wave LDS RAW -> lgkmcnt, no barrier needed) ----
        f32x4 oacc[2][2];
#pragma unroll
        for (int jj = 0; jj < 2; ++jj)
#pragma unroll
            for (int ct = 0; ct < 2; ++ct) oacc[jj][ct] = fzero;
#pragma unroll
        for (int jj = 0; jj < 2; ++jj)
#pragma unroll
            for (int ks = 0; ks < 2; ++ks) {
                f16x8 ap = *(const f16x8*)(P_s + (jj*64 + wave*16 + l15)*QKP_STRIDE + ks*32 + quad*8);
#pragma unroll
                for (int ct = 0; ct < 2; ++ct) {
                    f16x8 bv = *(const f16x8*)(vt_s + (jj*32 + ct*16 + l15)*VT_STRIDE + ks*32 + quad*8);
                    oacc[jj][ct] = __builtin_amdgcn_mfma_f32_16x16x32_f16(ap, bv, oacc[jj][ct], 0, 0, 0);
                }
            }
        __syncthreads();   // PV done reading vt -> oh may overwrite

        // deferred softmax normalization folded into the f16 convert
#pragma unroll
        for (int jj = 0; jj < 2; ++jj)
#pragma unroll
            for (int ct = 0; ct < 2; ++ct)
#pragma unroll
                for (int r = 0; r < 4; ++r)
                    oh_s[(wave*16 + quad*4 + r)*OH_STRIDE + jj*32 + ct*16 + l15] =
                        (_Float16)(oacc[jj][ct][r] * inv_r[jj][r]);
        __syncthreads();   // oh complete (cross-wave read next)

        // ---- Phase D: proj partial-K accumulate (K slice = this pair's 64 dims) ----
        f16x8 afr[4][2];
#pragma unroll
        for (int rt = 0; rt < 4; ++rt)
#pragma unroll
            for (int ks = 0; ks < 2; ++ks)
                afr[rt][ks] = *(const f16x8*)(oh_s + (rt*16 + l15)*OH_STRIDE + ks*32 + quad*8);
        __builtin_amdgcn_s_setprio(1);
#pragma unroll
        for (int cti = 0; cti < 3; ++cti) {
            const int n = (wave + 4*cti)*16 + l15;
#pragma unroll
            for (int ks = 0; ks < 2; ++ks) {
                f16x8 bf = *(const f16x8*)(pw16 + (size_t)n*192 + hp*64 + ks*32 + quad*8);
#pragma unroll
                for (int rt = 0; rt < 4; ++rt)
                    out_acc[cti][rt] =
                        __builtin_amdgcn_mfma_f32_16x16x32_f16(afr[rt][ks], bf, out_acc[cti][rt], 0, 0, 0);
            }
        }
        __builtin_amdgcn_s_setprio(0);
        __syncthreads();   // next iter overwrites qk (alias P) and vt (alias oh)
    }

    // ---- Epilogue ----
    if (SWS) {
        // f32 token-major window output; per store instruction the wave covers
        // 4 rows x 64B aligned segments -> full HBM lines, no RMW. Bias deferred.
        const size_t obase = (size_t)W * 12288;
#pragma unroll
        for (int cti = 0; cti < 3; ++cti) {
            const int n = (wave + 4*cti)*16 + l15;
#pragma unroll
            for (int rt = 0; rt < 4; ++rt)
#pragma unroll
                for (int r = 0; r < 4; ++r)
                    ows[obase + (size_t)(rt*16 + quad*4 + r)*192 + n] = out_acc[cti][rt][r];
        }
    } else {
        const int zA = wz*4 + 2;          // tokens z=0,1 (max 62 -> no wrap)
        const int zB = (wz*4 + 4) & 63;   // tokens z=2,3 (wraps only as full pair)
        const int yg = (wy*4 + quad + 2) & 63;
#pragma unroll
        for (int cti = 0; cti < 3; ++cti) {
            const int n = (wave + 4*cti)*16 + l15;
            const float bias = proj_b[n];
#pragma unroll
            for (int rt = 0; rt < 4; ++rt) {
                const int xg = (wx*4 + rt + 2) & 63;
                const size_t base = (((size_t)n*64 + (size_t)xg)*64 + (size_t)yg)*64;
                float2 v01 = { out_acc[cti][rt][0] + bias, out_acc[cti][rt][1] + bias };
                float2 v23 = { out_acc[cti][rt][2] + bias, out_acc[cti][rt][3] + bias };
                *(float2*)(out + base + zA) = v01;
                *(float2*)(out + base + zB) = v23;
            }
        }
    }
}

extern "C" void kernel_launch(void* const* d_in, const int* in_sizes, int n_in,
                              void* d_out, int out_size, void* d_ws, size_t ws_size,
                              hipStream_t stream) {
    const float* x      = (const float*)d_in[0];
    const float* qkv_w  = (const float*)d_in[1];
    const float* qkv_b  = (const float*)d_in[2];
    const float* proj_w = (const float*)d_in[3];
    const float* proj_b = (const float*)d_in[4];
    float* out = (float*)d_out;
    char* wsb = (char*)d_ws;
    _Float16* w16 = (_Float16*)wsb;

    cvt_weights_kernel<<<dim3(576), dim3(256), 0, stream>>>(qkv_w, proj_w, w16);

    if (ws_size >= (size_t)W16_BYTES + HWS_BYTES + OWS_BYTES) {
        _Float16* hws = (_Float16*)(wsb + W16_BYTES);
        float*    ows = (float*)(wsb + W16_BYTES + HWS_BYTES);
        gather_kernel<<<dim3(4096), dim3(256), 0, stream>>>(x, hws);
        win_attn_kernel<1,1><<<dim3(4096), dim3(256), SMEM_BYTES, stream>>>(
            x, w16, qkv_b, proj_b, out, hws, ows);
        scatter_kernel<<<dim3(4096), dim3(256), 0, stream>>>(ows, proj_b, out);
    } else if (ws_size >= (size_t)W16_BYTES + OWS_BYTES) {
        float* ows = (float*)(wsb + W16_BYTES);
        win_attn_kernel<0,1><<<dim3(4096), dim3(256), SMEM_BYTES, stream>>>(
            x, w16, qkv_b, proj_b, out, (const _Float16*)nullptr, ows);
        scatter_kernel<<<dim3(4096), dim3(256), 0, stream>>>(ows, proj_b, out);
    } else {
        win_attn_kernel<0,0><<<dim3(4096), dim3(256), SMEM_BYTES, stream>>>(
            x, w16, qkv_b, proj_b, out, (const _Float16*)nullptr, (float*)nullptr);
    }
}